// Round 1
// baseline (3304.583 us; speedup 1.0000x reference)
//
#include <hip/hip_runtime.h>

// ---------------------------------------------------------------------------
// types & helpers
// ---------------------------------------------------------------------------
using bf16x8 = __attribute__((ext_vector_type(8))) short;
using f32x4  = __attribute__((ext_vector_type(4))) float;
using as3_void  = __attribute__((address_space(3))) void;
using as1_cvoid = const __attribute__((address_space(1))) void;

__device__ __forceinline__ unsigned short f2bf(float x) {
    union { float f; unsigned u; } v; v.f = x;
    unsigned r = v.u + 0x7FFFu + ((v.u >> 16) & 1u);   // RNE
    return (unsigned short)(r >> 16);
}
__device__ __forceinline__ float bf2f(unsigned short h) {
    union { unsigned u; float f; } v; v.u = ((unsigned)h) << 16;
    return v.f;
}

// ---------------------------------------------------------------------------
// bf16 MFMA GEMM: C[M,N] (f32) = A[M,K] (bf16, row-major) @ Bt[N,K]^T (bf16)
// 128x128 tile, BK=64, 4 waves (2x2), 4x4 16x16x32 fragments per wave.
// grid.z = K-split; if >1 caller must memset C and we atomicAdd.
// LDS XOR-swizzle (chunk ^= row&7) applied on the GLOBAL source so
// global_load_lds (linear dest) + swizzled ds_read are conflict-free.
// ---------------------------------------------------------------------------
__global__ __launch_bounds__(256) void gemm_bf16(
    const unsigned short* __restrict__ A, const unsigned short* __restrict__ Bt,
    float* __restrict__ C, int M, int N, int K)
{
    __shared__ __align__(16) unsigned short As[128 * 64];
    __shared__ __align__(16) unsigned short Bs[128 * 64];
    const int tid  = threadIdx.x;
    const int lane = tid & 63, wave = tid >> 6;
    const int m0 = blockIdx.x * 128, n0 = blockIdx.y * 128;
    const int wr = wave >> 1, wc = wave & 1;
    const int rl = lane & 15, kg = lane >> 4;
    f32x4 acc[4][4] = {};

    const int kn   = K / gridDim.z;
    const int kbeg = blockIdx.z * kn;

    for (int kt = kbeg; kt < kbeg + kn; kt += 64) {
#pragma unroll
        for (int it = 0; it < 4; ++it) {
            int slot = it * 256 + tid;
            int r = slot >> 3, c = slot & 7;
            int cg = c ^ (r & 7);
            const unsigned short* ga = A  + (size_t)(m0 + r) * K + (kt + cg * 8);
            const unsigned short* gb = Bt + (size_t)(n0 + r) * K + (kt + cg * 8);
            __builtin_amdgcn_global_load_lds((as1_cvoid*)ga, (as3_void*)(As + slot * 8), 16, 0, 0);
            __builtin_amdgcn_global_load_lds((as1_cvoid*)gb, (as3_void*)(Bs + slot * 8), 16, 0, 0);
        }
        __syncthreads();
#pragma unroll
        for (int kh = 0; kh < 2; ++kh) {
            bf16x8 a_[4], b_[4];
#pragma unroll
            for (int i = 0; i < 4; ++i) {
                int ra = wr * 64 + i * 16 + rl;
                int ca = (kh * 4 + kg) ^ (ra & 7);
                a_[i] = *reinterpret_cast<const bf16x8*>(&As[ra * 64 + ca * 8]);
                int rb = wc * 64 + i * 16 + rl;
                int cb = (kh * 4 + kg) ^ (rb & 7);
                b_[i] = *reinterpret_cast<const bf16x8*>(&Bs[rb * 64 + cb * 8]);
            }
#pragma unroll
            for (int i = 0; i < 4; ++i)
#pragma unroll
                for (int j = 0; j < 4; ++j)
                    acc[i][j] = __builtin_amdgcn_mfma_f32_16x16x32_bf16(a_[i], b_[j], acc[i][j], 0, 0, 0);
        }
        __syncthreads();
    }

    const bool single = (gridDim.z == 1);
#pragma unroll
    for (int i = 0; i < 4; ++i)
#pragma unroll
        for (int j = 0; j < 4; ++j)
#pragma unroll
            for (int e = 0; e < 4; ++e) {
                int rr = m0 + wr * 64 + i * 16 + kg * 4 + e;
                int cc = n0 + wc * 64 + j * 16 + rl;
                if (single) C[(size_t)rr * N + cc] = acc[i][j][e];
                else        atomicAdd(&C[(size_t)rr * N + cc], acc[i][j][e]);
            }
}

// ---------------------------------------------------------------------------
// CSR build (edges constant -> rebuilt each launch, deterministic enough)
// ---------------------------------------------------------------------------
__global__ void csr_count(const int* __restrict__ edges, int E, int* __restrict__ cnt) {
    int e = blockIdx.x * 256 + threadIdx.x;
    if (e < E) atomicAdd(&cnt[edges[e]], 1);           // row0 = destinations
}

__global__ void csr_scan(const int* __restrict__ cnt, int n,
                         int* __restrict__ offs, int* __restrict__ cursor) {
    __shared__ int part[1024];
    int t = threadIdx.x;
    int per = n >> 10;                                  // 8 (N1) or 4 (N2)
    int base = t * per;
    int loc[8];
    int s = 0;
    for (int j = 0; j < per; ++j) { loc[j] = s; s += cnt[base + j]; }
    part[t] = s;
    __syncthreads();
    for (int o = 1; o < 1024; o <<= 1) {
        int v = (t >= o) ? part[t - o] : 0;
        __syncthreads();
        part[t] += v;
        __syncthreads();
    }
    int excl = (t == 0) ? 0 : part[t - 1];
    for (int j = 0; j < per; ++j) {
        int v = excl + loc[j];
        offs[base + j] = v;
        cursor[base + j] = v;
    }
    if (t == 1023) offs[n] = part[1023];
}

__global__ void csr_fill(const int* __restrict__ edges, int E,
                         int* __restrict__ cursor, int* __restrict__ srcs) {
    int e = blockIdx.x * 256 + threadIdx.x;
    if (e < E) {
        int d = edges[e], s = edges[E + e];
        int p = atomicAdd(&cursor[d], 1);
        srcs[p] = s;
    }
}

// T[i,:] = sum_{e in in(i)} Y[src_e,:] + (1+eps[l]) * Y[i,:]
__global__ void gather_csr(const float* __restrict__ Y, const int* __restrict__ offs,
                           const int* __restrict__ srcs, const float* __restrict__ epsv,
                           int l, float* __restrict__ T) {
    int i = blockIdx.x;
    int c = threadIdx.x;                                // 512 threads = 512 cols
    float e = 1.0f + epsv[l];
    int lo = offs[i], hi = offs[i + 1];
    float acc = e * Y[(size_t)i * 512 + c];
    for (int k = lo; k < hi; ++k)
        acc += Y[(size_t)srcs[k] * 512 + c];
    T[(size_t)i * 512 + c] = acc;
}

// ---------------------------------------------------------------------------
// BatchNorm (training-mode, biased var): stats then fused finalize+apply+ReLU
// ---------------------------------------------------------------------------
__global__ void bn_stats(const float* __restrict__ X, int M, float* __restrict__ ss) {
    int c = threadIdx.x;                                // 512 cols
    int rows = M / gridDim.x;
    int r0 = blockIdx.x * rows;
    float s = 0.f, s2 = 0.f;
    for (int r = 0; r < rows; ++r) {
        float v = X[(size_t)(r0 + r) * 512 + c];
        s += v; s2 += v * v;
    }
    atomicAdd(&ss[c], s);
    atomicAdd(&ss[512 + c], s2);
}

// out[r*ostride + ooff + c] = bf16( relu(alpha*x+beta) * (*scale or 1) )
__global__ void bn_apply(const float* __restrict__ X, int M, const float* __restrict__ ss,
                         const float* __restrict__ g, const float* __restrict__ b,
                         unsigned short* __restrict__ out, int ostride, int ooff,
                         const float* __restrict__ scale) {
    int c = threadIdx.x;
    float mean = ss[c] / (float)M;
    float var  = ss[512 + c] / (float)M - mean * mean;
    float al = g[c] * rsqrtf(var + 1e-5f);
    float be = b[c] - mean * al;
    float sc = scale ? *scale : 1.0f;
    int rows = M / gridDim.x;
    int r0 = blockIdx.x * rows;
    for (int r = 0; r < rows; ++r) {
        float v = al * X[(size_t)(r0 + r) * 512 + c] + be;
        v = fmaxf(v, 0.f) * sc;
        out[(size_t)(r0 + r) * ostride + ooff + c] = f2bf(v);
    }
}

// out[r*ostride+ooff+c] = bf16( (*scale or 1) * X[i] ), i = r*ncols+c
__global__ void scale_cvt(const float* __restrict__ X, const float* __restrict__ scale,
                          unsigned short* __restrict__ out, int ncols, int ostride,
                          int ooff, int total) {
    float sc = scale ? *scale : 1.0f;
    for (int i = blockIdx.x * blockDim.x + threadIdx.x; i < total; i += gridDim.x * blockDim.x) {
        int r = i / ncols, c = i - r * ncols;
        out[(size_t)r * ostride + ooff + c] = f2bf(sc * X[i]);
    }
}

// ---------------------------------------------------------------------------
// transposes (tiled through LDS)
// ---------------------------------------------------------------------------
__global__ void transpose_cvt(const float* __restrict__ S, unsigned short* __restrict__ D,
                              int rows, int cols) {  // D[c][r] = bf16(S[r][c])
    __shared__ unsigned short tile[32][33];
    int x0 = blockIdx.x * 32, y0 = blockIdx.y * 32;
    for (int j = threadIdx.y; j < 32; j += blockDim.y)
        tile[j][threadIdx.x] = f2bf(S[(size_t)(y0 + j) * cols + x0 + threadIdx.x]);
    __syncthreads();
    for (int j = threadIdx.y; j < 32; j += blockDim.y)
        D[(size_t)(x0 + j) * rows + y0 + threadIdx.x] = tile[threadIdx.x][j];
}

__global__ void transpose_bf16(const unsigned short* __restrict__ S, unsigned short* __restrict__ D,
                               int rows, int cols) { // D[c][r] = S[r][c]
    __shared__ unsigned short tile[32][33];
    int x0 = blockIdx.x * 32, y0 = blockIdx.y * 32;
    for (int j = threadIdx.y; j < 32; j += blockDim.y)
        tile[j][threadIdx.x] = S[(size_t)(y0 + j) * cols + x0 + threadIdx.x];
    __syncthreads();
    for (int j = threadIdx.y; j < 32; j += blockDim.y)
        D[(size_t)(x0 + j) * rows + y0 + threadIdx.x] = tile[threadIdx.x][j];
}

// ---------------------------------------------------------------------------
// graph pooling (graph_ids sorted -> binary-search row range per graph)
// ---------------------------------------------------------------------------
__device__ __forceinline__ int lbound(const int* __restrict__ a, int n, int v) {
    int lo = 0, hi = n;
    while (lo < hi) { int m = (lo + hi) >> 1; if (a[m] < v) lo = m + 1; else hi = m; }
    return lo;
}

__global__ void pool_bf16(const unsigned short* __restrict__ Hm, int cols,
                          const int* __restrict__ gid, int n, float* __restrict__ P) {
    int g = blockIdx.x;
    int lo = lbound(gid, n, g), hi = lbound(gid, n, g + 1);
    for (int c = threadIdx.x; c < cols; c += blockDim.x) {
        float s = 0.f;
        for (int i = lo; i < hi; ++i) s += bf2f(Hm[(size_t)i * cols + c]);
        P[(size_t)g * cols + c] = s;
    }
}

__global__ void pool_f32(const float* __restrict__ Hm, int cols,
                         const int* __restrict__ gid, int n, float* __restrict__ P) {
    int g = blockIdx.x;
    int lo = lbound(gid, n, g), hi = lbound(gid, n, g + 1);
    for (int c = threadIdx.x; c < cols; c += blockDim.x) {
        float s = 0.f;
        for (int i = lo; i < hi; ++i) s += Hm[(size_t)i * cols + c];
        P[(size_t)g * cols + c] = s;
    }
}

__global__ void softmax2(const float* __restrict__ atts, float* __restrict__ a) {
    if (threadIdx.x == 0) {
        float m = fmaxf(atts[0], atts[1]);
        float e0 = expf(atts[0] - m), e1 = expf(atts[1] - m);
        float inv = 1.0f / (e0 + e1);
        a[0] = e0 * inv; a[1] = e1 * inv;
    }
}

__global__ void score_kernel(const float* __restrict__ P0, const float* __restrict__ PL,
                             const float* __restrict__ W0, const float* __restrict__ b0,
                             const float* __restrict__ W, const float* __restrict__ bb,
                             float* __restrict__ out) {
    int g = blockIdx.x;
    int o = threadIdx.x;
    if (o >= 10) return;
    float s = b0[o];
    for (int k = 0; k < 128; ++k) s += P0[g * 128 + k] * W0[k * 10 + o];
    for (int l = 0; l < 4; ++l) {
        float t = bb[l * 10 + o];
        const float* p = PL + (size_t)l * 64 * 1024 + (size_t)g * 1024;
        const float* w = W + (size_t)l * 1024 * 10;
        for (int k = 0; k < 1024; ++k) t += p[k] * w[k * 10 + o];
        s += t;
    }
    out[g * 10 + o] = s;
}

// ---------------------------------------------------------------------------
// host orchestration
// ---------------------------------------------------------------------------
static void launch_gemm(const unsigned short* A, const unsigned short* Bt, float* C,
                        int M, int N, int K, hipStream_t s) {
    int bm = M / 128, bn = N / 128;
    int blocks = bm * bn;
    int ks = 1;
    while (blocks * ks < 512 && ((K / (ks * 2)) % 64 == 0) && ks < 8) ks <<= 1;
    if (ks > 1) hipMemsetAsync(C, 0, (size_t)M * N * sizeof(float), s);
    gemm_bf16<<<dim3(bm, bn, ks), dim3(256), 0, s>>>(A, Bt, C, M, N, K);
}

extern "C" void kernel_launch(void* const* d_in, const int* in_sizes, int n_in,
                              void* d_out, int out_size, void* d_ws, size_t ws_size,
                              hipStream_t stream) {
    const float* x1    = (const float*)d_in[0];
    const float* x2    = (const float*)d_in[1];
    const float* motif = (const float*)d_in[2];
    const int*   edge1 = (const int*)d_in[3];
    const int*   edge2 = (const int*)d_in[4];
    const int*   gid   = (const int*)d_in[5];
    const float* epsv  = (const float*)d_in[6];
    const float* atts  = (const float*)d_in[7];
    const float* m1W10 = (const float*)d_in[8];
    const float* m1W1r = (const float*)d_in[9];
    const float* m1bng = (const float*)d_in[11];
    const float* m1bnb = (const float*)d_in[12];
    const float* m1W2  = (const float*)d_in[13];
    const float* bn1g  = (const float*)d_in[15];
    const float* bn1b  = (const float*)d_in[16];
    const float* m2W10 = (const float*)d_in[17];
    const float* m2W1r = (const float*)d_in[18];
    const float* m2bng = (const float*)d_in[20];
    const float* m2bnb = (const float*)d_in[21];
    const float* m2W2  = (const float*)d_in[22];
    const float* bn2g  = (const float*)d_in[24];
    const float* bn2b  = (const float*)d_in[25];
    const float* pW0   = (const float*)d_in[26];
    const float* pb0   = (const float*)d_in[27];
    const float* pW    = (const float*)d_in[28];
    const float* pb    = (const float*)d_in[29];
    float* out = (float*)d_out;

    constexpr int N1 = 8192, N2 = 4096, E1 = 262144, E2 = 65536;

    char* base = (char*)d_ws;
    size_t off = 0;
    auto alloc = [&](size_t bytes) -> void* {
        void* p = base + off;
        off = (off + bytes + 255) & ~(size_t)255;
        return p;
    };

    // bf16 buffers
    unsigned short* motifT  = (unsigned short*)alloc((size_t)8192 * 4096 * 2);
    unsigned short* w1t1_0  = (unsigned short*)alloc((size_t)512 * 128 * 2);
    unsigned short* w1t1_r  = (unsigned short*)alloc((size_t)3 * 512 * 1024 * 2);
    unsigned short* w2t1    = (unsigned short*)alloc((size_t)4 * 512 * 512 * 2);
    unsigned short* w1t2_0  = (unsigned short*)alloc((size_t)512 * 64 * 2);
    unsigned short* w1t2_r  = (unsigned short*)alloc((size_t)3 * 512 * 512 * 2);
    unsigned short* w2t2    = (unsigned short*)alloc((size_t)4 * 512 * 512 * 2);
    unsigned short* x1b     = (unsigned short*)alloc((size_t)N1 * 128 * 2);
    unsigned short* x2b     = (unsigned short*)alloc((size_t)N2 * 64 * 2);
    unsigned short* H1b     = (unsigned short*)alloc((size_t)N1 * 1024 * 2);
    unsigned short* H2b     = (unsigned short*)alloc((size_t)N2 * 512 * 2);
    unsigned short* H2t     = (unsigned short*)alloc((size_t)512 * 4096 * 2);
    unsigned short* U1b     = (unsigned short*)alloc((size_t)N1 * 512 * 2);
    unsigned short* U2b     = (unsigned short*)alloc((size_t)N2 * 512 * 2);
    // f32 buffers (Y1 reused as R1; T1 reused as Cbig; Y2 reused as R2)
    float* Y1 = (float*)alloc((size_t)N1 * 512 * 4);
    float* T1 = (float*)alloc((size_t)N1 * 512 * 4);
    float* Y2 = (float*)alloc((size_t)N2 * 512 * 4);
    float* T2 = (float*)alloc((size_t)N2 * 512 * 4);
    // memset-together region: cnt1 | cnt2 | ss (all multiples of 256 bytes)
    int*   cnt1 = (int*)alloc((size_t)N1 * 4);
    int*   cnt2 = (int*)alloc((size_t)N2 * 4);
    float* ss   = (float*)alloc((size_t)16 * 1024 * 4);
    int*   offs1 = (int*)alloc((size_t)(N1 + 1) * 4);
    int*   offs2 = (int*)alloc((size_t)(N2 + 1) * 4);
    int*   cur1  = (int*)alloc((size_t)N1 * 4);
    int*   cur2  = (int*)alloc((size_t)N2 * 4);
    int*   srcs1 = (int*)alloc((size_t)E1 * 4);
    int*   srcs2 = (int*)alloc((size_t)E2 * 4);
    float* P0    = (float*)alloc((size_t)64 * 128 * 4);
    float* PL    = (float*)alloc((size_t)4 * 64 * 1024 * 4);
    float* aDev  = (float*)alloc(256);

    if (off > ws_size) return;  // insufficient workspace -> fail visibly

    // ---- setup ----
    hipMemsetAsync(cnt1, 0, (size_t)(N1 + N2) * 4 + 16 * 1024 * 4, stream);
    softmax2<<<1, 64, 0, stream>>>(atts, aDev);
    scale_cvt<<<1024, 256, 0, stream>>>(x1, nullptr, x1b, 128, 128, 0, N1 * 128);
    scale_cvt<<<512, 256, 0, stream>>>(x2, nullptr, x2b, 64, 64, 0, N2 * 64);
    transpose_cvt<<<dim3(8192 / 32, 4096 / 32), dim3(32, 8), 0, stream>>>(motif, motifT, 4096, 8192);
    transpose_cvt<<<dim3(16, 4), dim3(32, 8), 0, stream>>>(m1W10, w1t1_0, 128, 512);
    for (int i = 0; i < 3; ++i)
        transpose_cvt<<<dim3(16, 32), dim3(32, 8), 0, stream>>>(
            m1W1r + (size_t)i * 1024 * 512, w1t1_r + (size_t)i * 512 * 1024, 1024, 512);
    for (int l = 0; l < 4; ++l)
        transpose_cvt<<<dim3(16, 16), dim3(32, 8), 0, stream>>>(
            m1W2 + (size_t)l * 512 * 512, w2t1 + (size_t)l * 512 * 512, 512, 512);
    transpose_cvt<<<dim3(16, 2), dim3(32, 8), 0, stream>>>(m2W10, w1t2_0, 64, 512);
    for (int i = 0; i < 3; ++i)
        transpose_cvt<<<dim3(16, 16), dim3(32, 8), 0, stream>>>(
            m2W1r + (size_t)i * 512 * 512, w1t2_r + (size_t)i * 512 * 512, 512, 512);
    for (int l = 0; l < 4; ++l)
        transpose_cvt<<<dim3(16, 16), dim3(32, 8), 0, stream>>>(
            m2W2 + (size_t)l * 512 * 512, w2t2 + (size_t)l * 512 * 512, 512, 512);
    csr_count<<<E1 / 256, 256, 0, stream>>>(edge1, E1, cnt1);
    csr_count<<<E2 / 256, 256, 0, stream>>>(edge2, E2, cnt2);
    csr_scan<<<1, 1024, 0, stream>>>(cnt1, N1, offs1, cur1);
    csr_scan<<<1, 1024, 0, stream>>>(cnt2, N2, offs2, cur2);
    csr_fill<<<E1 / 256, 256, 0, stream>>>(edge1, E1, cur1, srcs1);
    csr_fill<<<E2 / 256, 256, 0, stream>>>(edge2, E2, cur2, srcs2);
    pool_f32<<<64, 256, 0, stream>>>(x1, 128, gid, N1, P0);

    // ---- layers ----
    for (int l = 0; l < 4; ++l) {
        // branch 1 (base graph, M = 8192)
        launch_gemm(l ? H1b : x1b,
                    l ? w1t1_r + (size_t)(l - 1) * 512 * 1024 : w1t1_0,
                    Y1, N1, 512, l ? 1024 : 128, stream);
        gather_csr<<<N1, 512, 0, stream>>>(Y1, offs1, srcs1, epsv, l, T1);
        bn_stats<<<64, 512, 0, stream>>>(T1, N1, ss + (size_t)(l * 4 + 0) * 1024);
        bn_apply<<<64, 512, 0, stream>>>(T1, N1, ss + (size_t)(l * 4 + 0) * 1024,
                                         m1bng + l * 512, m1bnb + l * 512, U1b, 512, 0, nullptr);
        launch_gemm(U1b, w2t1 + (size_t)l * 512 * 512, Y1 /*R1*/, N1, 512, 512, stream);
        bn_stats<<<64, 512, 0, stream>>>(Y1, N1, ss + (size_t)(l * 4 + 1) * 1024);
        bn_apply<<<64, 512, 0, stream>>>(Y1, N1, ss + (size_t)(l * 4 + 1) * 1024,
                                         bn1g + l * 512, bn1b + l * 512, H1b, 1024, 0, aDev + 0);
        // branch 2 (hyper graph, M = 4096)
        launch_gemm(l ? H2b : x2b,
                    l ? w1t2_r + (size_t)(l - 1) * 512 * 512 : w1t2_0,
                    Y2, N2, 512, l ? 512 : 64, stream);
        gather_csr<<<N2, 512, 0, stream>>>(Y2, offs2, srcs2, epsv, l, T2);
        bn_stats<<<32, 512, 0, stream>>>(T2, N2, ss + (size_t)(l * 4 + 2) * 1024);
        bn_apply<<<32, 512, 0, stream>>>(T2, N2, ss + (size_t)(l * 4 + 2) * 1024,
                                         m2bng + l * 512, m2bnb + l * 512, U2b, 512, 0, nullptr);
        launch_gemm(U2b, w2t2 + (size_t)l * 512 * 512, Y2 /*R2*/, N2, 512, 512, stream);
        bn_stats<<<32, 512, 0, stream>>>(Y2, N2, ss + (size_t)(l * 4 + 3) * 1024);
        bn_apply<<<32, 512, 0, stream>>>(Y2, N2, ss + (size_t)(l * 4 + 3) * 1024,
                                         bn2g + l * 512, bn2b + l * 512, H2b, 512, 0, nullptr);
        // fusion: h2A = motif2A^T @ h2 ; concat with attention
        transpose_bf16<<<dim3(16, 128), dim3(32, 8), 0, stream>>>(H2b, H2t, N2, 512);
        launch_gemm(motifT, H2t, T1 /*Cbig*/, N1, 512, 4096, stream);
        scale_cvt<<<2048, 256, 0, stream>>>(T1, aDev + 1, H1b, 512, 1024, 512, N1 * 512);
        // jumping-knowledge pooling of hidden[l+1]
        pool_bf16<<<64, 256, 0, stream>>>(H1b, 1024, gid, N1, PL + (size_t)l * 64 * 1024);
    }

    score_kernel<<<64, 64, 0, stream>>>(P0, PL, pW0, pb0, pW, pb, out);
}

// Round 2
// 2189.816 us; speedup vs baseline: 1.5091x; 1.5091x over previous
//
#include <hip/hip_runtime.h>

// ---------------------------------------------------------------------------
// types & helpers
// ---------------------------------------------------------------------------
using bf16x8 = __attribute__((ext_vector_type(8))) short;
using f32x4  = __attribute__((ext_vector_type(4))) float;
using u16x4  = __attribute__((ext_vector_type(4))) unsigned short;
using as3_void  = __attribute__((address_space(3))) void;
using as1_cvoid = const __attribute__((address_space(1))) void;

__device__ __forceinline__ unsigned short f2bf(float x) {
    union { float f; unsigned u; } v; v.f = x;
    unsigned r = v.u + 0x7FFFu + ((v.u >> 16) & 1u);   // RNE
    return (unsigned short)(r >> 16);
}
__device__ __forceinline__ float bf2f(unsigned short h) {
    union { unsigned u; float f; } v; v.u = ((unsigned)h) << 16;
    return v.f;
}

// ---------------------------------------------------------------------------
// bf16 MFMA GEMM: C[M,N] = A[M,K] (bf16 row-major) @ Bt[N,K]^T (bf16)
// BM=64, BN=128, BK=64; 4 waves (2 row x 2 col), each wave 32x64 = 2x4 frags.
// Epilogue: if Cb != null -> bf16 strided store of acc * (*scalep or 1);
//           else f32 store to Cf (ldc = N).
// LDS XOR-swizzle (chunk ^= row&7) applied on the GLOBAL source so
// global_load_lds (linear dest) + swizzled ds_read stay conflict-free.
// ---------------------------------------------------------------------------
__global__ __launch_bounds__(256) void gemm_bf16(
    const unsigned short* __restrict__ A, const unsigned short* __restrict__ Bt,
    int M, int N, int K,
    float* __restrict__ Cf, unsigned short* __restrict__ Cb,
    int ostride, int ooff, const float* __restrict__ scalep)
{
    __shared__ __align__(16) unsigned short As[64 * 64];
    __shared__ __align__(16) unsigned short Bs[128 * 64];
    const int tid  = threadIdx.x;
    const int lane = tid & 63, wave = tid >> 6;
    const int m0 = blockIdx.x * 64, n0 = blockIdx.y * 128;
    const int wr = wave >> 1, wc = wave & 1;
    const int rl = lane & 15, kg = lane >> 4;
    f32x4 acc[2][4] = {};

    for (int kt = 0; kt < K; kt += 64) {
#pragma unroll
        for (int it = 0; it < 2; ++it) {                 // A: 512 chunks
            int slot = it * 256 + tid;
            int r = slot >> 3, c = slot & 7;
            int cg = c ^ (r & 7);
            const unsigned short* ga = A + (size_t)(m0 + r) * K + (kt + cg * 8);
            __builtin_amdgcn_global_load_lds((as1_cvoid*)ga, (as3_void*)(As + slot * 8), 16, 0, 0);
        }
#pragma unroll
        for (int it = 0; it < 4; ++it) {                 // B: 1024 chunks
            int slot = it * 256 + tid;
            int r = slot >> 3, c = slot & 7;
            int cg = c ^ (r & 7);
            const unsigned short* gb = Bt + (size_t)(n0 + r) * K + (kt + cg * 8);
            __builtin_amdgcn_global_load_lds((as1_cvoid*)gb, (as3_void*)(Bs + slot * 8), 16, 0, 0);
        }
        __syncthreads();
#pragma unroll
        for (int kh = 0; kh < 2; ++kh) {
            bf16x8 a_[2], b_[4];
#pragma unroll
            for (int i = 0; i < 2; ++i) {
                int ra = wr * 32 + i * 16 + rl;
                int ca = (kh * 4 + kg) ^ (ra & 7);
                a_[i] = *reinterpret_cast<const bf16x8*>(&As[ra * 64 + ca * 8]);
            }
#pragma unroll
            for (int j = 0; j < 4; ++j) {
                int rb = wc * 64 + j * 16 + rl;
                int cb = (kh * 4 + kg) ^ (rb & 7);
                b_[j] = *reinterpret_cast<const bf16x8*>(&Bs[rb * 64 + cb * 8]);
            }
#pragma unroll
            for (int i = 0; i < 2; ++i)
#pragma unroll
                for (int j = 0; j < 4; ++j)
                    acc[i][j] = __builtin_amdgcn_mfma_f32_16x16x32_bf16(a_[i], b_[j], acc[i][j], 0, 0, 0);
        }
        __syncthreads();
    }

    if (Cb) {
        float sc = scalep ? *scalep : 1.0f;
#pragma unroll
        for (int i = 0; i < 2; ++i)
#pragma unroll
            for (int j = 0; j < 4; ++j)
#pragma unroll
                for (int e = 0; e < 4; ++e) {
                    int rr = m0 + wr * 32 + i * 16 + kg * 4 + e;
                    int cc = n0 + wc * 64 + j * 16 + rl;
                    Cb[(size_t)rr * ostride + ooff + cc] = f2bf(acc[i][j][e] * sc);
                }
    } else {
#pragma unroll
        for (int i = 0; i < 2; ++i)
#pragma unroll
            for (int j = 0; j < 4; ++j)
#pragma unroll
                for (int e = 0; e < 4; ++e) {
                    int rr = m0 + wr * 32 + i * 16 + kg * 4 + e;
                    int cc = n0 + wc * 64 + j * 16 + rl;
                    Cf[(size_t)rr * N + cc] = acc[i][j][e];
                }
    }
}

// ---------------------------------------------------------------------------
// CSR build (both edge lists in one pass each)
// ---------------------------------------------------------------------------
__global__ void csr_count2(const int* __restrict__ e1, int E1, int* __restrict__ c1,
                           const int* __restrict__ e2, int E2, int* __restrict__ c2) {
    int i = blockIdx.x * 256 + threadIdx.x;
    if (i < E1) atomicAdd(&c1[e1[i]], 1);
    else if (i < E1 + E2) atomicAdd(&c2[e2[i - E1]], 1);
}

__global__ void csr_scan2(const int* __restrict__ cnt1, int n1, int* __restrict__ offs1, int* __restrict__ cur1,
                          const int* __restrict__ cnt2, int n2, int* __restrict__ offs2, int* __restrict__ cur2) {
    const int* cnt = blockIdx.x ? cnt2 : cnt1;
    int n           = blockIdx.x ? n2 : n1;
    int* offs       = blockIdx.x ? offs2 : offs1;
    int* cursor     = blockIdx.x ? cur2 : cur1;
    __shared__ int part[1024];
    int t = threadIdx.x;
    int per = n >> 10;                                  // 8 (N1) or 4 (N2)
    int base = t * per;
    int loc[8];
    int s = 0;
    for (int j = 0; j < per; ++j) { loc[j] = s; s += cnt[base + j]; }
    part[t] = s;
    __syncthreads();
    for (int o = 1; o < 1024; o <<= 1) {
        int v = (t >= o) ? part[t - o] : 0;
        __syncthreads();
        part[t] += v;
        __syncthreads();
    }
    int excl = (t == 0) ? 0 : part[t - 1];
    for (int j = 0; j < per; ++j) {
        int v = excl + loc[j];
        offs[base + j] = v;
        cursor[base + j] = v;
    }
    if (t == 1023) offs[n] = part[1023];
}

__global__ void csr_fill2(const int* __restrict__ e1, int E1, int* __restrict__ cur1, int* __restrict__ s1,
                          const int* __restrict__ e2, int E2, int* __restrict__ cur2, int* __restrict__ s2) {
    int i = blockIdx.x * 256 + threadIdx.x;
    if (i < E1) {
        int d = e1[i], s = e1[E1 + i];
        s1[atomicAdd(&cur1[d], 1)] = s;
    } else if (i < E1 + E2) {
        int e = i - E1;
        int d = e2[e], s = e2[E2 + e];
        s2[atomicAdd(&cur2[d], 1)] = s;
    }
}

// T[i,:] = sum_{e in in(i)} Y[src_e,:] + (1+eps[l]) * Y[i,:]   (512 cols, float4)
__global__ void gather_csr(const f32x4* __restrict__ Y, const int* __restrict__ offs,
                           const int* __restrict__ srcs, const float* __restrict__ epsv,
                           int l, f32x4* __restrict__ T) {
    int i = blockIdx.x;
    int c = threadIdx.x;                                // 128 threads x float4
    float e = 1.0f + epsv[l];
    int lo = offs[i], hi = offs[i + 1];
    f32x4 acc = Y[(size_t)i * 128 + c];
    acc *= e;
    for (int k = lo; k < hi; ++k)
        acc += Y[(size_t)srcs[k] * 128 + c];
    T[(size_t)i * 128 + c] = acc;
}

// ---------------------------------------------------------------------------
// BatchNorm (training-mode, biased var)
// ---------------------------------------------------------------------------
__global__ void bn_stats(const f32x4* __restrict__ X, int M, float* __restrict__ ss) {
    int c = threadIdx.x;                                // 128 threads x 4 cols
    int rows = M / gridDim.x;
    int r0 = blockIdx.x * rows;
    f32x4 s = {}, s2 = {};
    for (int r = 0; r < rows; ++r) {
        f32x4 v = X[(size_t)(r0 + r) * 128 + c];
        s += v; s2 += v * v;
    }
#pragma unroll
    for (int i = 0; i < 4; ++i) {
        atomicAdd(&ss[c * 4 + i], s[i]);
        atomicAdd(&ss[512 + c * 4 + i], s2[i]);
    }
}

// out[r*ostride + ooff + 4c+i] = bf16( relu(al*x+be) * (*scale or 1) )
__global__ void bn_apply(const f32x4* __restrict__ X, int M, const float* __restrict__ ss,
                         const float* __restrict__ g, const float* __restrict__ b,
                         unsigned short* __restrict__ out, int ostride, int ooff,
                         const float* __restrict__ scale) {
    int c = threadIdx.x;                                // 128 threads x 4 cols
    float inv = 1.0f / (float)M;
    float al[4], be[4];
#pragma unroll
    for (int i = 0; i < 4; ++i) {
        float mean = ss[c * 4 + i] * inv;
        float var  = ss[512 + c * 4 + i] * inv - mean * mean;
        al[i] = g[c * 4 + i] * rsqrtf(var + 1e-5f);
        be[i] = b[c * 4 + i] - mean * al[i];
    }
    float sc = scale ? *scale : 1.0f;
    int rows = M / gridDim.x;
    int r0 = blockIdx.x * rows;
    for (int r = 0; r < rows; ++r) {
        f32x4 v = X[(size_t)(r0 + r) * 128 + c];
        u16x4 h;
#pragma unroll
        for (int i = 0; i < 4; ++i)
            h[i] = f2bf(fmaxf(al[i] * v[i] + be[i], 0.f) * sc);
        *reinterpret_cast<u16x4*>(out + (size_t)(r0 + r) * ostride + ooff + c * 4) = h;
    }
}

// contiguous f32 -> bf16 convert
__global__ void cvt_bf16(const f32x4* __restrict__ X, u16x4* __restrict__ out, int n4) {
    for (int i = blockIdx.x * blockDim.x + threadIdx.x; i < n4; i += gridDim.x * blockDim.x) {
        f32x4 v = X[i];
        u16x4 h;
#pragma unroll
        for (int j = 0; j < 4; ++j) h[j] = f2bf(v[j]);
        out[i] = h;
    }
}

// ---------------------------------------------------------------------------
// transposes (tiled through LDS); _b variant batches over grid.z
// ---------------------------------------------------------------------------
__global__ void transpose_cvt_b(const float* __restrict__ S, unsigned short* __restrict__ D,
                                int rows, int cols, size_t sstride, size_t dstride) {
    S += blockIdx.z * sstride; D += blockIdx.z * dstride;
    __shared__ unsigned short tile[32][33];
    int x0 = blockIdx.x * 32, y0 = blockIdx.y * 32;
    for (int j = threadIdx.y; j < 32; j += blockDim.y)
        tile[j][threadIdx.x] = f2bf(S[(size_t)(y0 + j) * cols + x0 + threadIdx.x]);
    __syncthreads();
    for (int j = threadIdx.y; j < 32; j += blockDim.y)
        D[(size_t)(x0 + j) * rows + y0 + threadIdx.x] = tile[threadIdx.x][j];
}

// the 11 square 512x512 weight matrices in one launch: z<4 -> m1W2, z<7 -> m2W1r, else m2W2
__global__ void transpose_cvt11(const float* __restrict__ A, unsigned short* __restrict__ Ad,
                                const float* __restrict__ B, unsigned short* __restrict__ Bd,
                                const float* __restrict__ Cs, unsigned short* __restrict__ Cd) {
    int z = blockIdx.z;
    const float* S; unsigned short* D;
    if (z < 4)      { S = A  + (size_t)z * 262144;       D = Ad + (size_t)z * 262144; }
    else if (z < 7) { S = B  + (size_t)(z - 4) * 262144; D = Bd + (size_t)(z - 4) * 262144; }
    else            { S = Cs + (size_t)(z - 7) * 262144; D = Cd + (size_t)(z - 7) * 262144; }
    __shared__ unsigned short tile[32][33];
    int x0 = blockIdx.x * 32, y0 = blockIdx.y * 32;
    for (int j = threadIdx.y; j < 32; j += blockDim.y)
        tile[j][threadIdx.x] = f2bf(S[(size_t)(y0 + j) * 512 + x0 + threadIdx.x]);
    __syncthreads();
    for (int j = threadIdx.y; j < 32; j += blockDim.y)
        D[(size_t)(x0 + j) * 512 + y0 + threadIdx.x] = tile[threadIdx.x][j];
}

__global__ void transpose_bf16(const unsigned short* __restrict__ S, unsigned short* __restrict__ D,
                               int rows, int cols) { // D[c][r] = S[r][c]
    __shared__ unsigned short tile[32][33];
    int x0 = blockIdx.x * 32, y0 = blockIdx.y * 32;
    for (int j = threadIdx.y; j < 32; j += blockDim.y)
        tile[j][threadIdx.x] = S[(size_t)(y0 + j) * cols + x0 + threadIdx.x];
    __syncthreads();
    for (int j = threadIdx.y; j < 32; j += blockDim.y)
        D[(size_t)(x0 + j) * rows + y0 + threadIdx.x] = tile[threadIdx.x][j];
}

// ---------------------------------------------------------------------------
// graph pooling (graph_ids sorted -> binary-search row range per graph)
// ---------------------------------------------------------------------------
__device__ __forceinline__ int lbound(const int* __restrict__ a, int n, int v) {
    int lo = 0, hi = n;
    while (lo < hi) { int m = (lo + hi) >> 1; if (a[m] < v) lo = m + 1; else hi = m; }
    return lo;
}

__global__ void pool_bf16(const u16x4* __restrict__ Hm, const int* __restrict__ gid,
                          int n, float* __restrict__ P) {   // 1024 cols
    int g = blockIdx.x;
    int lo = lbound(gid, n, g), hi = lbound(gid, n, g + 1);
    int c = threadIdx.x;                                 // 256 threads x 4 cols
    f32x4 s = {};
    for (int i = lo; i < hi; ++i) {
        u16x4 v = Hm[(size_t)i * 256 + c];
#pragma unroll
        for (int j = 0; j < 4; ++j) s[j] += bf2f(v[j]);
    }
#pragma unroll
    for (int j = 0; j < 4; ++j)
        P[(size_t)g * 1024 + c * 4 + j] = s[j];
}

__global__ void pool_f32(const float* __restrict__ Hm, int cols,
                         const int* __restrict__ gid, int n, float* __restrict__ P) {
    int g = blockIdx.x;
    int lo = lbound(gid, n, g), hi = lbound(gid, n, g + 1);
    for (int c = threadIdx.x; c < cols; c += blockDim.x) {
        float s = 0.f;
        for (int i = lo; i < hi; ++i) s += Hm[(size_t)i * cols + c];
        P[(size_t)g * cols + c] = s;
    }
}

__global__ void softmax2(const float* __restrict__ atts, float* __restrict__ a) {
    if (threadIdx.x == 0) {
        float m = fmaxf(atts[0], atts[1]);
        float e0 = expf(atts[0] - m), e1 = expf(atts[1] - m);
        float inv = 1.0f / (e0 + e1);
        a[0] = e0 * inv; a[1] = e1 * inv;
    }
}

// score[g,o] = P0[g]@W0 + b0 + sum_l PL[l][g]@W[l] + b[l]
// 64 blocks (one per graph) x 256 threads; k-parallel + wave/LDS reduce.
__global__ __launch_bounds__(256) void score_kernel(
    const float* __restrict__ P0, const float* __restrict__ PL,
    const float* __restrict__ W0, const float* __restrict__ b0,
    const float* __restrict__ W, const float* __restrict__ bb,
    float* __restrict__ out)
{
    int g = blockIdx.x;
    int t = threadIdx.x;
    float part[10];
#pragma unroll
    for (int o = 0; o < 10; ++o) part[o] = 0.f;
    if (t < 128) {
        float p = P0[g * 128 + t];
#pragma unroll
        for (int o = 0; o < 10; ++o) part[o] += p * W0[t * 10 + o];
    }
    for (int l = 0; l < 4; ++l) {
        const float* p = PL + (size_t)l * 65536 + (size_t)g * 1024;
        const float* w = W + (size_t)l * 10240;
        for (int k = t; k < 1024; k += 256) {
            float pv = p[k];
#pragma unroll
            for (int o = 0; o < 10; ++o) part[o] += pv * w[k * 10 + o];
        }
    }
    __shared__ float red[4][10];
#pragma unroll
    for (int o = 0; o < 10; ++o) {
        float v = part[o];
        for (int off = 32; off; off >>= 1) v += __shfl_down(v, off, 64);
        if ((t & 63) == 0) red[t >> 6][o] = v;
    }
    __syncthreads();
    if (t < 10) {
        float s = b0[t] + red[0][t] + red[1][t] + red[2][t] + red[3][t];
#pragma unroll
        for (int l = 0; l < 4; ++l) s += bb[l * 10 + t];
        out[g * 10 + t] = s;
    }
}

// ---------------------------------------------------------------------------
// host orchestration
// ---------------------------------------------------------------------------
static void launch_gemm(const unsigned short* A, const unsigned short* Bt,
                        int M, int N, int K, float* Cf, unsigned short* Cb,
                        int ostride, int ooff, const float* scalep, hipStream_t s) {
    gemm_bf16<<<dim3(M / 64, N / 128), 256, 0, s>>>(A, Bt, M, N, K, Cf, Cb, ostride, ooff, scalep);
}

extern "C" void kernel_launch(void* const* d_in, const int* in_sizes, int n_in,
                              void* d_out, int out_size, void* d_ws, size_t ws_size,
                              hipStream_t stream) {
    const float* x1    = (const float*)d_in[0];
    const float* x2    = (const float*)d_in[1];
    const float* motif = (const float*)d_in[2];
    const int*   edge1 = (const int*)d_in[3];
    const int*   edge2 = (const int*)d_in[4];
    const int*   gid   = (const int*)d_in[5];
    const float* epsv  = (const float*)d_in[6];
    const float* atts  = (const float*)d_in[7];
    const float* m1W10 = (const float*)d_in[8];
    const float* m1W1r = (const float*)d_in[9];
    const float* m1bng = (const float*)d_in[11];
    const float* m1bnb = (const float*)d_in[12];
    const float* m1W2  = (const float*)d_in[13];
    const float* bn1g  = (const float*)d_in[15];
    const float* bn1b  = (const float*)d_in[16];
    const float* m2W10 = (const float*)d_in[17];
    const float* m2W1r = (const float*)d_in[18];
    const float* m2bng = (const float*)d_in[20];
    const float* m2bnb = (const float*)d_in[21];
    const float* m2W2  = (const float*)d_in[22];
    const float* bn2g  = (const float*)d_in[24];
    const float* bn2b  = (const float*)d_in[25];
    const float* pW0   = (const float*)d_in[26];
    const float* pb0   = (const float*)d_in[27];
    const float* pW    = (const float*)d_in[28];
    const float* pb    = (const float*)d_in[29];
    float* out = (float*)d_out;

    constexpr int N1 = 8192, N2 = 4096, E1 = 262144, E2 = 65536;

    char* base = (char*)d_ws;
    size_t off = 0;
    auto alloc = [&](size_t bytes) -> void* {
        void* p = base + off;
        off = (off + bytes + 255) & ~(size_t)255;
        return p;
    };

    // bf16 buffers
    unsigned short* motifT  = (unsigned short*)alloc((size_t)8192 * 4096 * 2);
    unsigned short* w1t1_0  = (unsigned short*)alloc((size_t)512 * 128 * 2);
    unsigned short* w1t1_r  = (unsigned short*)alloc((size_t)3 * 512 * 1024 * 2);
    unsigned short* w2t1    = (unsigned short*)alloc((size_t)4 * 512 * 512 * 2);
    unsigned short* w1t2_0  = (unsigned short*)alloc((size_t)512 * 64 * 2);
    unsigned short* w1t2_r  = (unsigned short*)alloc((size_t)3 * 512 * 512 * 2);
    unsigned short* w2t2    = (unsigned short*)alloc((size_t)4 * 512 * 512 * 2);
    unsigned short* x1b     = (unsigned short*)alloc((size_t)N1 * 128 * 2);
    unsigned short* x2b     = (unsigned short*)alloc((size_t)N2 * 64 * 2);
    unsigned short* H1b     = (unsigned short*)alloc((size_t)N1 * 1024 * 2);
    unsigned short* H2b     = (unsigned short*)alloc((size_t)N2 * 512 * 2);
    unsigned short* H2t     = (unsigned short*)alloc((size_t)512 * 4096 * 2);
    unsigned short* U1b     = (unsigned short*)alloc((size_t)N1 * 512 * 2);
    unsigned short* U2b     = (unsigned short*)alloc((size_t)N2 * 512 * 2);
    // f32 buffers
    float* Y1 = (float*)alloc((size_t)N1 * 512 * 4);
    float* T1 = (float*)alloc((size_t)N1 * 512 * 4);
    float* Y2 = (float*)alloc((size_t)N2 * 512 * 4);
    float* T2 = (float*)alloc((size_t)N2 * 512 * 4);
    // memset-together region: cnt1 | cnt2 | ss (all multiples of 256 bytes)
    int*   cnt1 = (int*)alloc((size_t)N1 * 4);
    int*   cnt2 = (int*)alloc((size_t)N2 * 4);
    float* ss   = (float*)alloc((size_t)16 * 1024 * 4);
    int*   offs1 = (int*)alloc((size_t)(N1 + 1) * 4);
    int*   offs2 = (int*)alloc((size_t)(N2 + 1) * 4);
    int*   cur1  = (int*)alloc((size_t)N1 * 4);
    int*   cur2  = (int*)alloc((size_t)N2 * 4);
    int*   srcs1 = (int*)alloc((size_t)E1 * 4);
    int*   srcs2 = (int*)alloc((size_t)E2 * 4);
    float* P0    = (float*)alloc((size_t)64 * 128 * 4);
    float* PL    = (float*)alloc((size_t)4 * 64 * 1024 * 4);
    float* aDev  = (float*)alloc(256);

    if (off > ws_size) return;  // insufficient workspace -> fail visibly

    // ---- setup ----
    hipMemsetAsync(cnt1, 0, (size_t)(N1 + N2) * 4 + 16 * 1024 * 4, stream);
    softmax2<<<1, 64, 0, stream>>>(atts, aDev);
    cvt_bf16<<<512, 256, 0, stream>>>((const f32x4*)x1, (u16x4*)x1b, N1 * 128 / 4);
    cvt_bf16<<<256, 256, 0, stream>>>((const f32x4*)x2, (u16x4*)x2b, N2 * 64 / 4);
    transpose_cvt_b<<<dim3(256, 128, 1), dim3(32, 8), 0, stream>>>(motif, motifT, 4096, 8192, 0, 0);
    transpose_cvt_b<<<dim3(16, 4, 1), dim3(32, 8), 0, stream>>>(m1W10, w1t1_0, 128, 512, 0, 0);
    transpose_cvt_b<<<dim3(16, 32, 3), dim3(32, 8), 0, stream>>>(m1W1r, w1t1_r, 1024, 512,
                                                                 (size_t)1024 * 512, (size_t)512 * 1024);
    transpose_cvt_b<<<dim3(16, 2, 1), dim3(32, 8), 0, stream>>>(m2W10, w1t2_0, 64, 512, 0, 0);
    transpose_cvt11<<<dim3(16, 16, 11), dim3(32, 8), 0, stream>>>(m1W2, w2t1, m2W1r, w1t2_r, m2W2, w2t2);
    csr_count2<<<(E1 + E2) / 256, 256, 0, stream>>>(edge1, E1, cnt1, edge2, E2, cnt2);
    csr_scan2<<<2, 1024, 0, stream>>>(cnt1, N1, offs1, cur1, cnt2, N2, offs2, cur2);
    csr_fill2<<<(E1 + E2) / 256, 256, 0, stream>>>(edge1, E1, cur1, srcs1, edge2, E2, cur2, srcs2);
    pool_f32<<<64, 128, 0, stream>>>(x1, 128, gid, N1, P0);

    // ---- layers ----
    for (int l = 0; l < 4; ++l) {
        // branch 1 (base graph, M = 8192)
        launch_gemm(l ? H1b : x1b,
                    l ? w1t1_r + (size_t)(l - 1) * 512 * 1024 : w1t1_0,
                    N1, 512, l ? 1024 : 128, Y1, nullptr, 0, 0, nullptr, stream);
        gather_csr<<<N1, 128, 0, stream>>>((const f32x4*)Y1, offs1, srcs1, epsv, l, (f32x4*)T1);
        bn_stats<<<64, 128, 0, stream>>>((const f32x4*)T1, N1, ss + (size_t)(l * 4 + 0) * 1024);
        bn_apply<<<64, 128, 0, stream>>>((const f32x4*)T1, N1, ss + (size_t)(l * 4 + 0) * 1024,
                                         m1bng + l * 512, m1bnb + l * 512, U1b, 512, 0, nullptr);
        launch_gemm(U1b, w2t1 + (size_t)l * 512 * 512, N1, 512, 512, Y1, nullptr, 0, 0, nullptr, stream);
        bn_stats<<<64, 128, 0, stream>>>((const f32x4*)Y1, N1, ss + (size_t)(l * 4 + 1) * 1024);
        bn_apply<<<64, 128, 0, stream>>>((const f32x4*)Y1, N1, ss + (size_t)(l * 4 + 1) * 1024,
                                         bn1g + l * 512, bn1b + l * 512, H1b, 1024, 0, aDev + 0);
        // branch 2 (hyper graph, M = 4096)
        launch_gemm(l ? H2b : x2b,
                    l ? w1t2_r + (size_t)(l - 1) * 512 * 512 : w1t2_0,
                    N2, 512, l ? 512 : 64, Y2, nullptr, 0, 0, nullptr, stream);
        gather_csr<<<N2, 128, 0, stream>>>((const f32x4*)Y2, offs2, srcs2, epsv, l, (f32x4*)T2);
        bn_stats<<<32, 128, 0, stream>>>((const f32x4*)T2, N2, ss + (size_t)(l * 4 + 2) * 1024);
        bn_apply<<<32, 128, 0, stream>>>((const f32x4*)T2, N2, ss + (size_t)(l * 4 + 2) * 1024,
                                         m2bng + l * 512, m2bnb + l * 512, U2b, 512, 0, nullptr);
        launch_gemm(U2b, w2t2 + (size_t)l * 512 * 512, N2, 512, 512, Y2, nullptr, 0, 0, nullptr, stream);
        bn_stats<<<32, 128, 0, stream>>>((const f32x4*)Y2, N2, ss + (size_t)(l * 4 + 3) * 1024);
        bn_apply<<<32, 128, 0, stream>>>((const f32x4*)Y2, N2, ss + (size_t)(l * 4 + 3) * 1024,
                                         bn2g + l * 512, bn2b + l * 512, H2b, 512, 0, nullptr);
        // fusion: h2A = motif2A^T @ h2, fused bf16 epilogue writes concat half
        transpose_bf16<<<dim3(16, 128), dim3(32, 8), 0, stream>>>(H2b, H2t, N2, 512);
        launch_gemm(motifT, H2t, N1, 512, 4096, nullptr, H1b, 1024, 512, aDev + 1, stream);
        // jumping-knowledge pooling of hidden[l+1]
        pool_bf16<<<64, 256, 0, stream>>>((const u16x4*)H1b, gid, N1, PL + (size_t)l * 64 * 1024);
    }

    score_kernel<<<64, 256, 0, stream>>>(P0, PL, pW0, pb0, pW, pb, out);
}